// Round 10
// baseline (276.855 us; speedup 1.0000x reference)
//
#include <hip/hip_runtime.h>
#include <hip/hip_bf16.h>
#include <hip/hip_cooperative_groups.h>

namespace cg = cooperative_groups;

#define BATCH 32
#define NN 4096
#define KK 32

typedef __attribute__((ext_vector_type(8))) short bf16x8;
typedef __attribute__((ext_vector_type(4))) float f32x4;

// ws float offsets.  SMP (written by K4) overlaps PART/WCOMB/KP, all dead by then.
#define WS_PART   0          // 32*16*256 = 131072
#define WS_WCOMB  131072     // 65536
#define WS_KP     196608     // 262144 (raw silu output; LN applied on the fly)
#define WS_SMP    0          // 5*131072 = 655360 (K4 only)
#define WS_G      655360     // 131072 floats = 262144 bf16

__device__ __forceinline__ unsigned short f2bf(float x) {
  unsigned int u = __float_as_uint(x);
  u += 0x7fffu + ((u >> 16) & 1u);   // RTNE
  return (unsigned short)(u >> 16);
}

__device__ __forceinline__ unsigned int pk2(float lo, float hi) {
  union { __hip_bfloat162 b; unsigned int u; } c;
  c.b = __float22bfloat162_rn(float2{lo, hi});   // v_cvt_pk_bf16_f32
  return c.u;
}

// =============== shared stage bodies (used by coop kernel AND fallbacks) ===============

__device__ __forceinline__ void stageA_body(
    int bk, int t, const float* __restrict__ h, const float* __restrict__ Wsrc,
    const float* __restrict__ Wdst, float* __restrict__ ws,
    float4* __restrict__ out4, int n4, float* smem /*>=1024 floats*/) {
  int zi = bk * 256 + t;
  if (zi < n4) out4[zi] = float4{0.f, 0.f, 0.f, 0.f};
  if (bk < 512) {
    // block (b, p) sums rows p*256..p*256+255 of h[b]
    int b = bk >> 4, p = bk & 15;
    int c4 = t & 63, rg = t >> 6;
    const float4* hp = (const float4*)h + (((size_t)(b * NN + p * 256)) << 6) + c4;
    float4 acc = {0.f, 0.f, 0.f, 0.f};
    for (int r = rg; r < 256; r += 4) {
      float4 v = hp[(size_t)r << 6];
      acc.x += v.x; acc.y += v.y; acc.z += v.z; acc.w += v.w;
    }
    float4* sm = (float4*)smem;
    sm[t] = acc;
    __syncthreads();
    if (t < 64) {
      float4 a = sm[t], b2 = sm[t + 64], c = sm[t + 128], d = sm[t + 192];
      float4 tot = {a.x + b2.x + c.x + d.x, a.y + b2.y + c.y + d.y,
                    a.z + b2.z + c.z + d.z, a.w + b2.w + c.w + d.w};
      ((float4*)(ws + WS_PART))[(size_t)(b * 16 + p) * 64 + t] = tot;
    }
  } else {
    // wcomb[dp][d] = sum_e Wdst[e][dp] * Wsrc[e][d]
    int dp = bk - 512;
    float acc = 0.f;
#pragma unroll 8
    for (int e = 0; e < 256; e++) acc += Wdst[e * 256 + dp] * Wsrc[e * 256 + t];
    ws[WS_WCOMB + dp * 256 + t] = acc;
  }
}

__device__ __forceinline__ void stageB_body(
    int bk, int t, const float* __restrict__ Wkp, const float* __restrict__ bkp,
    float* __restrict__ ws, float* meanLds /*8192 floats*/) {
  for (int idx = t; idx < 8192; idx += 256) {
    int b = idx >> 8, d = idx & 255;
    float s = 0.f;
#pragma unroll
    for (int p = 0; p < 16; p++) s += ws[WS_PART + (size_t)(b * 16 + p) * 256 + d];
    meanLds[idx] = s * (1.0f / NN);
  }
  __syncthreads();
  int j = bk * 128 + (t & 127);
  int bh = (t >> 7) * 16;
  const float4* wrow = (const float4*)(Wkp + (size_t)j * 256);
  float acc[16];
#pragma unroll
  for (int i = 0; i < 16; i++) acc[i] = 0.f;
  for (int d4 = 0; d4 < 64; d4++) {
    float4 wv = wrow[d4];
#pragma unroll
    for (int i = 0; i < 16; i++) {
      float4 m = ((const float4*)meanLds)[(bh + i) * 64 + d4];
      acc[i] += wv.x * m.x + wv.y * m.y + wv.z * m.z + wv.w * m.w;
    }
  }
  float bb = bkp[j];
#pragma unroll
  for (int i = 0; i < 16; i++) {
    float x = acc[i] + bb;
    ws[WS_KP + (size_t)(bh + i) * 8192 + j] = x / (1.0f + __expf(-x));
  }
}

__device__ __forceinline__ void stageC_body(
    int bx, int b, int t, const float* __restrict__ gamma,
    const float* __restrict__ beta, float* __restrict__ ws,
    float* kpl /*8192 floats*/, float* red /*8 floats*/) {
  const float* kp = ws + WS_KP + (size_t)b * 8192;
  float4* kpl4 = (float4*)kpl;
  float4 v[8];
  float s = 0.f, sq = 0.f;
#pragma unroll
  for (int i = 0; i < 8; i++) {
    v[i] = ((const float4*)kp)[t + i * 256];
    s += v[i].x + v[i].y + v[i].z + v[i].w;
    sq += v[i].x * v[i].x + v[i].y * v[i].y + v[i].z * v[i].z + v[i].w * v[i].w;
  }
#pragma unroll
  for (int o = 1; o < 64; o <<= 1) { s += __shfl_xor(s, o); sq += __shfl_xor(sq, o); }
  int w = t >> 6, lane = t & 63;
  if (lane == 0) { red[w] = s; red[4 + w] = sq; }
  __syncthreads();
  float S = red[0] + red[1] + red[2] + red[3];
  float SQ = red[4] + red[5] + red[6] + red[7];
  float mu = S * (1.0f / 8192.0f);
  float var = fmaxf(SQ * (1.0f / 8192.0f) - mu * mu, 0.f);
  float rs = rsqrtf(var + 1e-5f);
#pragma unroll
  for (int i = 0; i < 8; i++) {
    float4 g4 = ((const float4*)gamma)[t + i * 256];
    float4 b4 = ((const float4*)beta)[t + i * 256];
    float4 o;
    o.x = ((v[i].x - mu) * rs * g4.x + b4.x) * 0.0625f;
    o.y = ((v[i].y - mu) * rs * g4.y + b4.y) * 0.0625f;
    o.z = ((v[i].z - mu) * rs * g4.z + b4.z) * 0.0625f;
    o.w = ((v[i].w - mu) * rs * g4.w + b4.w) * 0.0625f;
    kpl4[t + i * 256] = o;
  }
  __syncthreads();
  int dc = bx >> 1, kh = bx & 1;
  int d = dc * 64 + lane;
  int k0 = kh * 16 + w * 4;
  const float* wc = ws + WS_WCOMB;
  float acc[4] = {0.f, 0.f, 0.f, 0.f};
#pragma unroll 4
  for (int dp4 = 0; dp4 < 64; dp4++) {
    float w0 = wc[(dp4 * 4 + 0) * 256 + d];
    float w1 = wc[(dp4 * 4 + 1) * 256 + d];
    float w2 = wc[(dp4 * 4 + 2) * 256 + d];
    float w3 = wc[(dp4 * 4 + 3) * 256 + d];
#pragma unroll
    for (int i = 0; i < 4; i++) {
      float4 kv = kpl4[(k0 + i) * 64 + dp4];   // wave-uniform -> LDS broadcast
      acc[i] += kv.x * w0 + kv.y * w1 + kv.z * w2 + kv.w * w3;
    }
  }
  unsigned short* g = (unsigned short*)(ws + WS_G);
#pragma unroll
  for (int i = 0; i < 4; i++) {
    g[(size_t)(b * KK + k0 + i) * 256 + d] = f2bf(acc[i]);
  }
}

// =============== KA: cooperative fused k1+k2+k3 ===============
__global__ __launch_bounds__(256, 4) void kA_fused(
    const float* __restrict__ h, const float* __restrict__ Wsrc,
    const float* __restrict__ Wdst, const float* __restrict__ Wkp,
    const float* __restrict__ bkp, const float* __restrict__ gamma,
    const float* __restrict__ beta, float* __restrict__ ws,
    float4* __restrict__ out4, int n4) {
  cg::grid_group grid = cg::this_grid();
  __shared__ __align__(16) float smem[8192];   // 32 KB, reused per stage
  __shared__ float red[8];
  int bk = blockIdx.x, t = threadIdx.x;

  stageA_body(bk, t, h, Wsrc, Wdst, ws, out4, n4, smem);
  grid.sync();
  if (bk < 64) stageB_body(bk, t, Wkp, bkp, ws, smem);
  grid.sync();
  if (bk < 256) stageC_body(bk & 7, bk >> 3, t, gamma, beta, ws, smem, red);
}

// =============== fallback separate kernels (round-9 structure) ===============
__global__ __launch_bounds__(256, 4) void k1_sep(
    const float* __restrict__ h, const float* __restrict__ Wsrc,
    const float* __restrict__ Wdst, float* __restrict__ ws,
    float4* __restrict__ out4, int n4) {
  __shared__ __align__(16) float smem[1024];
  stageA_body(blockIdx.x, threadIdx.x, h, Wsrc, Wdst, ws, out4, n4, smem);
}

__global__ __launch_bounds__(256, 2) void k2_sep(
    const float* __restrict__ Wkp, const float* __restrict__ bkp,
    float* __restrict__ ws) {
  __shared__ __align__(16) float smem[8192];
  stageB_body(blockIdx.x, threadIdx.x, Wkp, bkp, ws, smem);
}

__global__ __launch_bounds__(256, 2) void k3_sep(
    const float* __restrict__ gamma, const float* __restrict__ beta,
    float* __restrict__ ws) {
  __shared__ __align__(16) float smem[8192];
  __shared__ float red[8];
  stageC_body(blockIdx.x, blockIdx.y, threadIdx.x, gamma, beta, ws, smem, red);
}

// ---------------- K4: attention partials (fp32 h, in-register bf16 convert) ----------------
__global__ __launch_bounds__(256, 4) void k4_attn(
    const float* __restrict__ h, const float* __restrict__ pos,
    const unsigned short* __restrict__ gbuf, float* __restrict__ ws) {
  __shared__ __align__(16) unsigned short glds[8192];  // 16 KB, XOR-swizzled
  const int s = blockIdx.x, b = blockIdx.y, t = threadIdx.x;
  const int lane = t & 63, w = t >> 6;
  const int l15 = lane & 15, l4 = lane >> 4;
  const float LOG2E = 1.4426950408889634f;
  {
    const float4* gsrc = (const float4*)(gbuf + (size_t)b * 8192);
    float4* gdst = (float4*)glds;
    for (int i = t; i < 1024; i += 256) {
      int k = i >> 5, c = i & 31;
      gdst[k * 32 + (c ^ (k & 7))] = gsrc[i];   // T2 swizzle
    }
  }
  __syncthreads();
  const bf16x8* gl = (const bf16x8*)glds;
  const int sw = l15 & 7;

  float m0 = -3.0e38f, m1 = -3.0e38f;
  float L0 = 0.f, L1 = 0.f;
  float P0x = 0.f, P0y = 0.f, P0z = 0.f, P1x = 0.f, P1y = 0.f, P1z = 0.f;

  for (int tile = 0; tile < 2; tile++) {
    int nbase = s * 128 + tile * 64 + w * 16;
    const float4* hp = (const float4*)(h + ((size_t)(b * NN + nbase + l15) << 8));
    int co = l4 * 2;
    f32x4 acc0 = {0.f, 0.f, 0.f, 0.f}, acc1 = {0.f, 0.f, 0.f, 0.f};
#pragma unroll
    for (int kd = 0; kd < 8; kd++) {
      float4 v0 = hp[kd * 8 + co];
      float4 v1 = hp[kd * 8 + co + 1];
      union { unsigned int u[4]; bf16x8 v; } au;
      au.u[0] = pk2(v0.x, v0.y); au.u[1] = pk2(v0.z, v0.w);
      au.u[2] = pk2(v1.x, v1.y); au.u[3] = pk2(v1.z, v1.w);
      int cidx = (kd * 4 + l4) ^ sw;
      bf16x8 g0 = gl[l15 * 32 + cidx];
      bf16x8 g1 = gl[(16 + l15) * 32 + cidx];
      acc0 = __builtin_amdgcn_mfma_f32_16x16x32_bf16(au.v, g0, acc0, 0, 0, 0);
      acc1 = __builtin_amdgcn_mfma_f32_16x16x32_bf16(au.v, g1, acc1, 0, 0, 0);
    }
    float px[4], py[4], pz[4];
#pragma unroll
    for (int j = 0; j < 4; j++) {
      const float* pp = pos + (size_t)(b * NN + nbase + l4 * 4 + j) * 3;
      px[j] = pp[0]; py[j] = pp[1]; pz[j] = pp[2];
    }
    {
      float tm = fmaxf(fmaxf(acc0[0], acc0[1]), fmaxf(acc0[2], acc0[3]));
      tm = fmaxf(tm, __shfl_xor(tm, 16));
      tm = fmaxf(tm, __shfl_xor(tm, 32));
      float mn = fmaxf(m0, tm);
      float corr = exp2f((m0 - mn) * LOG2E);
      float e0 = exp2f((acc0[0] - mn) * LOG2E);
      float e1 = exp2f((acc0[1] - mn) * LOG2E);
      float e2 = exp2f((acc0[2] - mn) * LOG2E);
      float e3 = exp2f((acc0[3] - mn) * LOG2E);
      float se = e0 + e1 + e2 + e3;
      float sx = e0 * px[0] + e1 * px[1] + e2 * px[2] + e3 * px[3];
      float sy = e0 * py[0] + e1 * py[1] + e2 * py[2] + e3 * py[3];
      float sz = e0 * pz[0] + e1 * pz[1] + e2 * pz[2] + e3 * pz[3];
      se += __shfl_xor(se, 16); se += __shfl_xor(se, 32);
      sx += __shfl_xor(sx, 16); sx += __shfl_xor(sx, 32);
      sy += __shfl_xor(sy, 16); sy += __shfl_xor(sy, 32);
      sz += __shfl_xor(sz, 16); sz += __shfl_xor(sz, 32);
      L0 = L0 * corr + se; P0x = P0x * corr + sx;
      P0y = P0y * corr + sy; P0z = P0z * corr + sz; m0 = mn;
    }
    {
      float tm = fmaxf(fmaxf(acc1[0], acc1[1]), fmaxf(acc1[2], acc1[3]));
      tm = fmaxf(tm, __shfl_xor(tm, 16));
      tm = fmaxf(tm, __shfl_xor(tm, 32));
      float mn = fmaxf(m1, tm);
      float corr = exp2f((m1 - mn) * LOG2E);
      float e0 = exp2f((acc1[0] - mn) * LOG2E);
      float e1 = exp2f((acc1[1] - mn) * LOG2E);
      float e2 = exp2f((acc1[2] - mn) * LOG2E);
      float e3 = exp2f((acc1[3] - mn) * LOG2E);
      float se = e0 + e1 + e2 + e3;
      float sx = e0 * px[0] + e1 * px[1] + e2 * px[2] + e3 * px[3];
      float sy = e0 * py[0] + e1 * py[1] + e2 * py[2] + e3 * py[3];
      float sz = e0 * pz[0] + e1 * pz[1] + e2 * pz[2] + e3 * pz[3];
      se += __shfl_xor(se, 16); se += __shfl_xor(se, 32);
      sx += __shfl_xor(sx, 16); sx += __shfl_xor(sx, 32);
      sy += __shfl_xor(sy, 16); sy += __shfl_xor(sy, 32);
      sz += __shfl_xor(sz, 16); sz += __shfl_xor(sz, 32);
      L1 = L1 * corr + se; P1x = P1x * corr + sx;
      P1y = P1y * corr + sy; P1z = P1z * corr + sz; m1 = mn;
    }
  }
  if (lane < 32) {
    int kt = lane >> 4;
    float mv = kt ? m1 : m0;
    float lv = kt ? L1 : L0;
    float pxv = kt ? P1x : P0x;
    float pyv = kt ? P1y : P0y;
    float pzv = kt ? P1z : P0z;
    size_t base = ((size_t)(b * KK + lane)) * 128 + s * 4 + w;
    ws[WS_SMP + base] = mv;
    ws[WS_SMP + 131072 + base] = lv;
    ws[WS_SMP + 262144 + base] = pxv;
    ws[WS_SMP + 393216 + base] = pyv;
    ws[WS_SMP + 524288 + base] = pzv;
  }
}

// ---------------- K5: combine partials -> kp_pos (one block per b) ----------------
__global__ void k5_final(const float* __restrict__ smp, float* __restrict__ out) {
  int b = blockIdx.x, t = threadIdx.x;
  const float LOG2E = 1.4426950408889634f;
  int k = t >> 3, sub = t & 7;          // 8 threads per keypoint
  size_t base = ((size_t)(b * KK + k)) * 128;
  float M = -3.0e38f;
#pragma unroll 4
  for (int j = sub; j < 128; j += 8) M = fmaxf(M, smp[base + j]);
#pragma unroll
  for (int o = 1; o < 8; o <<= 1) M = fmaxf(M, __shfl_xor(M, o));
  float L = 0.f, X = 0.f, Y = 0.f, Z = 0.f;
#pragma unroll 4
  for (int j = sub; j < 128; j += 8) {
    float f = exp2f((smp[base + j] - M) * LOG2E);
    L += smp[131072 + base + j] * f;
    X += smp[262144 + base + j] * f;
    Y += smp[393216 + base + j] * f;
    Z += smp[524288 + base + j] * f;
  }
#pragma unroll
  for (int o = 1; o < 8; o <<= 1) {
    L += __shfl_xor(L, o); X += __shfl_xor(X, o);
    Y += __shfl_xor(Y, o); Z += __shfl_xor(Z, o);
  }
  if (sub == 0) {
    float inv = 1.0f / L;
    out[(b * KK + k) * 3 + 0] = X * inv;
    out[(b * KK + k) * 3 + 1] = Y * inv;
    out[(b * KK + k) * 3 + 2] = Z * inv;
  }
}

extern "C" void kernel_launch(void* const* d_in, const int* in_sizes, int n_in,
                              void* d_out, int out_size, void* d_ws, size_t ws_size,
                              hipStream_t stream) {
  const float* h     = (const float*)d_in[0];
  const float* pos   = (const float*)d_in[1];
  const float* Wsrc  = (const float*)d_in[2];
  const float* Wdst  = (const float*)d_in[3];
  const float* Wkp   = (const float*)d_in[4];
  const float* bkp   = (const float*)d_in[5];
  const float* gamma = (const float*)d_in[6];
  const float* beta  = (const float*)d_in[7];
  float* out = (float*)d_out;
  float* ws  = (float*)d_ws;
  float4* out4 = (float4*)d_out;
  int n4 = out_size / 4;

  void* args[] = {(void*)&h, (void*)&Wsrc, (void*)&Wdst, (void*)&Wkp,
                  (void*)&bkp, (void*)&gamma, (void*)&beta, (void*)&ws,
                  (void*)&out4, (void*)&n4};
  hipError_t err = hipLaunchCooperativeKernel((const void*)kA_fused, dim3(768),
                                              dim3(256), args, 0, stream);
  if (err != hipSuccess) {
    k1_sep<<<768, 256, 0, stream>>>(h, Wsrc, Wdst, ws, out4, n4);
    k2_sep<<<64, 256, 0, stream>>>(Wkp, bkp, ws);
    k3_sep<<<dim3(8, BATCH), 256, 0, stream>>>(gamma, beta, ws);
  }
  k4_attn<<<dim3(32, BATCH), 256, 0, stream>>>(h, pos,
                                               (const unsigned short*)(ws + WS_G),
                                               ws);
  k5_final<<<BATCH, 256, 0, stream>>>(ws + WS_SMP, out);
}

// Round 11
// 102.606 us; speedup vs baseline: 2.6982x; 2.6982x over previous
//
#include <hip/hip_runtime.h>
#include <hip/hip_bf16.h>

#define BATCH 32
#define NN 4096
#define KK 32

typedef __attribute__((ext_vector_type(8))) short bf16x8;
typedef __attribute__((ext_vector_type(4))) float f32x4;

// ws float offsets.  SMP (written by K4) overlaps PART/WCOMB/KP, all dead by then.
#define WS_PART   0          // 32*16*256 = 131072
#define WS_WCOMB  131072     // 65536
#define WS_KP     196608     // 262144 (raw silu output; LN applied on the fly in K3)
#define WS_SMP    0          // 5*131072 = 655360 (K4 only)
#define WS_G      655360     // 131072 floats = 262144 bf16

__device__ __forceinline__ unsigned short f2bf(float x) {
  unsigned int u = __float_as_uint(x);
  u += 0x7fffu + ((u >> 16) & 1u);   // RTNE
  return (unsigned short)(u >> 16);
}

__device__ __forceinline__ unsigned int pk2(float lo, float hi) {
  union { __hip_bfloat162 b; unsigned int u; } c;
  c.b = __float22bfloat162_rn(float2{lo, hi});   // v_cvt_pk_bf16_f32
  return c.u;
}

// ---------------- K1: zero out, colsum partials, wcomb ----------------
__global__ __launch_bounds__(256, 4) void k1_sum_wcomb(
    const float* __restrict__ h, const float* __restrict__ Wsrc,
    const float* __restrict__ Wdst, float* __restrict__ ws,
    float4* __restrict__ out4, int n4) {
  __shared__ float4 sm[256];
  int bk = blockIdx.x, t = threadIdx.x;
  int zi = bk * 256 + t;
  if (zi < n4) out4[zi] = float4{0.f, 0.f, 0.f, 0.f};
  if (bk < 512) {
    // block (b, p) sums rows p*256..p*256+255 of h[b]
    int b = bk >> 4, p = bk & 15;
    int c4 = t & 63, rg = t >> 6;
    const float4* hp = (const float4*)h + (((size_t)(b * NN + p * 256)) << 6) + c4;
    float4 acc = {0.f, 0.f, 0.f, 0.f};
#pragma unroll 4
    for (int r = rg; r < 256; r += 4) {
      float4 v = hp[(size_t)r << 6];
      acc.x += v.x; acc.y += v.y; acc.z += v.z; acc.w += v.w;
    }
    sm[t] = acc;
    __syncthreads();
    if (t < 64) {
      float4 a = sm[t], b2 = sm[t + 64], c = sm[t + 128], d = sm[t + 192];
      float4 tot = {a.x + b2.x + c.x + d.x, a.y + b2.y + c.y + d.y,
                    a.z + b2.z + c.z + d.z, a.w + b2.w + c.w + d.w};
      ((float4*)(ws + WS_PART))[(size_t)(b * 16 + p) * 64 + t] = tot;
    }
  } else {
    // wcomb[dp][d] = sum_e Wdst[e][dp] * Wsrc[e][d]
    int dp = bk - 512;
    float acc = 0.f;
#pragma unroll 8
    for (int e = 0; e < 256; e++) acc += Wdst[e * 256 + dp] * Wsrc[e * 256 + t];
    ws[WS_WCOMB + dp * 256 + t] = acc;
  }
}

// ---------------- K2: means + kp = silu(mean @ Wkp^T + b), j-split ----------------
__global__ __launch_bounds__(256, 2) void k2_kp(
    const float* __restrict__ Wkp, const float* __restrict__ bkp,
    float* __restrict__ ws) {
  __shared__ float meanLds[32 * 256];   // 32 KB
  int bk = blockIdx.x, t = threadIdx.x;   // 64 blocks
  // means reduce, float4-vectorized (2048 float4s over 256 threads)
  {
    float4* ml4 = (float4*)meanLds;
    const float4* part4 = (const float4*)(ws + WS_PART);
    for (int idx = t; idx < 2048; idx += 256) {
      int b = idx >> 6, d4 = idx & 63;
      float4 s = {0.f, 0.f, 0.f, 0.f};
#pragma unroll
      for (int p = 0; p < 16; p++) {
        float4 v = part4[(size_t)(b * 16 + p) * 64 + d4];
        s.x += v.x; s.y += v.y; s.z += v.z; s.w += v.w;
      }
      s.x *= (1.0f / NN); s.y *= (1.0f / NN);
      s.z *= (1.0f / NN); s.w *= (1.0f / NN);
      ml4[idx] = s;
    }
  }
  __syncthreads();
  int j = bk * 128 + (t & 127);
  int bh = (t >> 7) * 16;
  const float4* wrow = (const float4*)(Wkp + (size_t)j * 256);
  float acc[16];
#pragma unroll
  for (int i = 0; i < 16; i++) acc[i] = 0.f;
  for (int d4 = 0; d4 < 64; d4++) {
    float4 wv = wrow[d4];
#pragma unroll
    for (int i = 0; i < 16; i++) {
      float4 m = ((const float4*)meanLds)[(bh + i) * 64 + d4];
      acc[i] += wv.x * m.x + wv.y * m.y + wv.z * m.z + wv.w * m.w;
    }
  }
  float bb = bkp[j];
#pragma unroll
  for (int i = 0; i < 16; i++) {
    float x = acc[i] + bb;
    ws[WS_KP + (size_t)(bh + i) * 8192 + j] = x / (1.0f + __expf(-x));
  }
}

// ---------------- K3: fused LN + g = (LN(kp) @ wcomb)/16 -> bf16 (LDS, coalesced) ----------------
__global__ __launch_bounds__(256, 2) void k3_ln_g(
    const float* __restrict__ ws_in, const float* __restrict__ gamma,
    const float* __restrict__ beta, float* __restrict__ ws) {
  __shared__ float kpl[8192];    // 32 KB: normalized kp row (with 1/16 folded)
  __shared__ float red[8];
  int bx = blockIdx.x, b = blockIdx.y, t = threadIdx.x;
  const float* kp = ws_in + WS_KP + (size_t)b * 8192;
  float4* kpl4 = (float4*)kpl;
  // load kp row to registers, compute LN stats
  float4 v[8];
  float s = 0.f, sq = 0.f;
#pragma unroll
  for (int i = 0; i < 8; i++) {
    v[i] = ((const float4*)kp)[t + i * 256];
    s += v[i].x + v[i].y + v[i].z + v[i].w;
    sq += v[i].x * v[i].x + v[i].y * v[i].y + v[i].z * v[i].z + v[i].w * v[i].w;
  }
#pragma unroll
  for (int o = 1; o < 64; o <<= 1) { s += __shfl_xor(s, o); sq += __shfl_xor(sq, o); }
  int w = t >> 6, lane = t & 63;
  if (lane == 0) { red[w] = s; red[4 + w] = sq; }
  __syncthreads();
  float S = red[0] + red[1] + red[2] + red[3];
  float SQ = red[4] + red[5] + red[6] + red[7];
  float mu = S * (1.0f / 8192.0f);
  float var = fmaxf(SQ * (1.0f / 8192.0f) - mu * mu, 0.f);
  float rs = rsqrtf(var + 1e-5f);
  // normalize into LDS, folding the 1/sqrt(256) score scale (exact pow2)
#pragma unroll
  for (int i = 0; i < 8; i++) {
    float4 g4 = ((const float4*)gamma)[t + i * 256];
    float4 b4 = ((const float4*)beta)[t + i * 256];
    float4 o;
    o.x = ((v[i].x - mu) * rs * g4.x + b4.x) * 0.0625f;
    o.y = ((v[i].y - mu) * rs * g4.y + b4.y) * 0.0625f;
    o.z = ((v[i].z - mu) * rs * g4.z + b4.z) * 0.0625f;
    o.w = ((v[i].w - mu) * rs * g4.w + b4.w) * 0.0625f;
    kpl4[t + i * 256] = o;
  }
  __syncthreads();
  // g phase: full-wave coalesced wcomb loads; wave-uniform kpl broadcasts
  int dc = bx >> 1, kh = bx & 1;
  int d = dc * 64 + lane;                 // 64 consecutive d per wave
  int k0 = kh * 16 + w * 4;               // each wave owns 4 k's
  const float* wc = ws_in + WS_WCOMB;
  float acc[4] = {0.f, 0.f, 0.f, 0.f};
#pragma unroll 4
  for (int dp4 = 0; dp4 < 64; dp4++) {
    float w0 = wc[(dp4 * 4 + 0) * 256 + d];
    float w1 = wc[(dp4 * 4 + 1) * 256 + d];
    float w2 = wc[(dp4 * 4 + 2) * 256 + d];
    float w3 = wc[(dp4 * 4 + 3) * 256 + d];
#pragma unroll
    for (int i = 0; i < 4; i++) {
      float4 kv = kpl4[(k0 + i) * 64 + dp4];   // wave-uniform -> LDS broadcast
      acc[i] += kv.x * w0 + kv.y * w1 + kv.z * w2 + kv.w * w3;
    }
  }
  unsigned short* g = (unsigned short*)(ws + WS_G);
#pragma unroll
  for (int i = 0; i < 4; i++) {
    g[(size_t)(b * KK + k0 + i) * 256 + d] = f2bf(acc[i]);
  }
}

// ---------------- K4: attention partials (fp32 h, in-register bf16 convert) ----------------
__global__ __launch_bounds__(256, 4) void k4_attn(
    const float* __restrict__ h, const float* __restrict__ pos,
    const unsigned short* __restrict__ gbuf, float* __restrict__ ws) {
  __shared__ __align__(16) unsigned short glds[8192];  // 16 KB, XOR-swizzled
  const int s = blockIdx.x, b = blockIdx.y, t = threadIdx.x;
  const int lane = t & 63, w = t >> 6;
  const int l15 = lane & 15, l4 = lane >> 4;
  const float LOG2E = 1.4426950408889634f;
  {
    const float4* gsrc = (const float4*)(gbuf + (size_t)b * 8192);
    float4* gdst = (float4*)glds;
    for (int i = t; i < 1024; i += 256) {
      int k = i >> 5, c = i & 31;
      gdst[k * 32 + (c ^ (k & 7))] = gsrc[i];   // T2 swizzle
    }
  }
  __syncthreads();
  const bf16x8* gl = (const bf16x8*)glds;
  const int sw = l15 & 7;

  float m0 = -3.0e38f, m1 = -3.0e38f;
  float L0 = 0.f, L1 = 0.f;
  float P0x = 0.f, P0y = 0.f, P0z = 0.f, P1x = 0.f, P1y = 0.f, P1z = 0.f;

  for (int tile = 0; tile < 2; tile++) {
    int nbase = s * 128 + tile * 64 + w * 16;
    const float4* hp = (const float4*)(h + ((size_t)(b * NN + nbase + l15) << 8));
    int co = l4 * 2;
    // pos for this lane's 4 rows: 48B contiguous, 16B-aligned -> 3 float4 loads
    int prow = nbase + l4 * 4;
    const float4* pp4 = (const float4*)(pos + (size_t)(b * NN + prow) * 3);
    float4 pA = pp4[0], pB = pp4[1], pC = pp4[2];
    float px[4] = {pA.x, pA.w, pB.z, pC.y};
    float py[4] = {pA.y, pB.x, pB.w, pC.z};
    float pz[4] = {pA.z, pB.y, pC.x, pC.w};
    f32x4 acc0 = {0.f, 0.f, 0.f, 0.f}, acc1 = {0.f, 0.f, 0.f, 0.f};
#pragma unroll
    for (int kd = 0; kd < 8; kd++) {
      float4 v0 = hp[kd * 8 + co];
      float4 v1 = hp[kd * 8 + co + 1];
      union { unsigned int u[4]; bf16x8 v; } au;
      au.u[0] = pk2(v0.x, v0.y); au.u[1] = pk2(v0.z, v0.w);
      au.u[2] = pk2(v1.x, v1.y); au.u[3] = pk2(v1.z, v1.w);
      int cidx = (kd * 4 + l4) ^ sw;
      bf16x8 g0 = gl[l15 * 32 + cidx];
      bf16x8 g1 = gl[(16 + l15) * 32 + cidx];
      acc0 = __builtin_amdgcn_mfma_f32_16x16x32_bf16(au.v, g0, acc0, 0, 0, 0);
      acc1 = __builtin_amdgcn_mfma_f32_16x16x32_bf16(au.v, g1, acc1, 0, 0, 0);
    }
    {
      float tm = fmaxf(fmaxf(acc0[0], acc0[1]), fmaxf(acc0[2], acc0[3]));
      tm = fmaxf(tm, __shfl_xor(tm, 16));
      tm = fmaxf(tm, __shfl_xor(tm, 32));
      float mn = fmaxf(m0, tm);
      float corr = exp2f((m0 - mn) * LOG2E);
      float e0 = exp2f((acc0[0] - mn) * LOG2E);
      float e1 = exp2f((acc0[1] - mn) * LOG2E);
      float e2 = exp2f((acc0[2] - mn) * LOG2E);
      float e3 = exp2f((acc0[3] - mn) * LOG2E);
      float se = e0 + e1 + e2 + e3;
      float sx = e0 * px[0] + e1 * px[1] + e2 * px[2] + e3 * px[3];
      float sy = e0 * py[0] + e1 * py[1] + e2 * py[2] + e3 * py[3];
      float sz = e0 * pz[0] + e1 * pz[1] + e2 * pz[2] + e3 * pz[3];
      se += __shfl_xor(se, 16); se += __shfl_xor(se, 32);
      sx += __shfl_xor(sx, 16); sx += __shfl_xor(sx, 32);
      sy += __shfl_xor(sy, 16); sy += __shfl_xor(sy, 32);
      sz += __shfl_xor(sz, 16); sz += __shfl_xor(sz, 32);
      L0 = L0 * corr + se; P0x = P0x * corr + sx;
      P0y = P0y * corr + sy; P0z = P0z * corr + sz; m0 = mn;
    }
    {
      float tm = fmaxf(fmaxf(acc1[0], acc1[1]), fmaxf(acc1[2], acc1[3]));
      tm = fmaxf(tm, __shfl_xor(tm, 16));
      tm = fmaxf(tm, __shfl_xor(tm, 32));
      float mn = fmaxf(m1, tm);
      float corr = exp2f((m1 - mn) * LOG2E);
      float e0 = exp2f((acc1[0] - mn) * LOG2E);
      float e1 = exp2f((acc1[1] - mn) * LOG2E);
      float e2 = exp2f((acc1[2] - mn) * LOG2E);
      float e3 = exp2f((acc1[3] - mn) * LOG2E);
      float se = e0 + e1 + e2 + e3;
      float sx = e0 * px[0] + e1 * px[1] + e2 * px[2] + e3 * px[3];
      float sy = e0 * py[0] + e1 * py[1] + e2 * py[2] + e3 * py[3];
      float sz = e0 * pz[0] + e1 * pz[1] + e2 * pz[2] + e3 * pz[3];
      se += __shfl_xor(se, 16); se += __shfl_xor(se, 32);
      sx += __shfl_xor(sx, 16); sx += __shfl_xor(sx, 32);
      sy += __shfl_xor(sy, 16); sy += __shfl_xor(sy, 32);
      sz += __shfl_xor(sz, 16); sz += __shfl_xor(sz, 32);
      L1 = L1 * corr + se; P1x = P1x * corr + sx;
      P1y = P1y * corr + sy; P1z = P1z * corr + sz; m1 = mn;
    }
  }
  if (lane < 32) {
    int kt = lane >> 4;
    float mv = kt ? m1 : m0;
    float lv = kt ? L1 : L0;
    float pxv = kt ? P1x : P0x;
    float pyv = kt ? P1y : P0y;
    float pzv = kt ? P1z : P0z;
    size_t base = ((size_t)(b * KK + lane)) * 128 + s * 4 + w;
    ws[WS_SMP + base] = mv;
    ws[WS_SMP + 131072 + base] = lv;
    ws[WS_SMP + 262144 + base] = pxv;
    ws[WS_SMP + 393216 + base] = pyv;
    ws[WS_SMP + 524288 + base] = pzv;
  }
}

// ---------------- K5: combine partials -> kp_pos (one block per b) ----------------
__global__ void k5_final(const float* __restrict__ smp, float* __restrict__ out) {
  int b = blockIdx.x, t = threadIdx.x;
  const float LOG2E = 1.4426950408889634f;
  int k = t >> 3, sub = t & 7;          // 8 threads per keypoint
  size_t base = ((size_t)(b * KK + k)) * 128;
  float M = -3.0e38f;
#pragma unroll 4
  for (int j = sub; j < 128; j += 8) M = fmaxf(M, smp[base + j]);
#pragma unroll
  for (int o = 1; o < 8; o <<= 1) M = fmaxf(M, __shfl_xor(M, o));
  float L = 0.f, X = 0.f, Y = 0.f, Z = 0.f;
#pragma unroll 4
  for (int j = sub; j < 128; j += 8) {
    float f = exp2f((smp[base + j] - M) * LOG2E);
    L += smp[131072 + base + j] * f;
    X += smp[262144 + base + j] * f;
    Y += smp[393216 + base + j] * f;
    Z += smp[524288 + base + j] * f;
  }
#pragma unroll
  for (int o = 1; o < 8; o <<= 1) {
    L += __shfl_xor(L, o); X += __shfl_xor(X, o);
    Y += __shfl_xor(Y, o); Z += __shfl_xor(Z, o);
  }
  if (sub == 0) {
    float inv = 1.0f / L;
    out[(b * KK + k) * 3 + 0] = X * inv;
    out[(b * KK + k) * 3 + 1] = Y * inv;
    out[(b * KK + k) * 3 + 2] = Z * inv;
  }
}

extern "C" void kernel_launch(void* const* d_in, const int* in_sizes, int n_in,
                              void* d_out, int out_size, void* d_ws, size_t ws_size,
                              hipStream_t stream) {
  const float* h     = (const float*)d_in[0];
  const float* pos   = (const float*)d_in[1];
  const float* Wsrc  = (const float*)d_in[2];
  const float* Wdst  = (const float*)d_in[3];
  const float* Wkp   = (const float*)d_in[4];
  const float* bkp   = (const float*)d_in[5];
  const float* gamma = (const float*)d_in[6];
  const float* beta  = (const float*)d_in[7];
  float* out = (float*)d_out;
  float* ws  = (float*)d_ws;

  k1_sum_wcomb<<<768, 256, 0, stream>>>(h, Wsrc, Wdst, ws, (float4*)d_out,
                                        out_size / 4);
  k2_kp<<<64, 256, 0, stream>>>(Wkp, bkp, ws);
  k3_ln_g<<<dim3(8, BATCH), 256, 0, stream>>>(ws, gamma, beta, ws);
  k4_attn<<<dim3(32, BATCH), 256, 0, stream>>>(h, pos,
                                               (const unsigned short*)(ws + WS_G),
                                               ws);
  k5_final<<<BATCH, 256, 0, stream>>>(ws + WS_SMP, out);
}